// Round 1
// baseline (394.435 us; speedup 1.0000x reference)
//
#include <hip/hip_runtime.h>

// TemplatePointwiseAttention, MI355X/gfx950.
// Fold Wq@Wk^T and Wv@Wo per head (T=4 keys, softmax between two linear maps)
// -> two bf16 MFMA GEMMs (K=128, K=256) + tiny 4-way softmax, fully fused.
// This revision: 32-pair blocks (32 KB LDS, acc[8]) so 4 blocks/CU are
// co-resident (16 waves/CU vs 8 before) — the kernel is phase-serialized and
// latency-bound (MfmaUtil 4%, VALUBusy 19%, Occupancy 22%), so residency is
// the lever. Attention phase: 2 lanes per (p,h), 32 channels each, one
// shfl_xor(1) to combine logits; b128 LDS reads (2-way bank alias = free).

#define R_   384
#define P_   (R_ * R_)     // 147456 residue pairs
#define PB   32            // pairs per block
#define NBLK (P_ / PB)     // 4608 blocks

typedef __attribute__((ext_vector_type(8))) short  short8;   // 8 x bf16 MFMA frag
typedef __attribute__((ext_vector_type(4))) float  f32x4;    // MFMA accumulator

__device__ __forceinline__ unsigned short f2bf(float f) {
  unsigned u = __float_as_uint(f);
  unsigned r = ((u >> 16) & 1u) + 0x7FFFu;   // RNE
  return (unsigned short)((u + r) >> 16);
}
__device__ __forceinline__ float bf2f(unsigned short s) {
  return __uint_as_float(((unsigned)s) << 16);
}
// LDS layout for [p][c] tiles (p<32, c<256), bf16, pitch 256, XOR-swizzled in
// 16B blocks so both "lanes vary p" (attention) and MFMA A-frag reads avoid
// bank conflicts.
__device__ __forceinline__ int swz(int p, int c) {
  return p * 256 + ((((c >> 3) ^ (p & 31)) << 3) | (c & 7));
}

// ---- K0: fold weights into AbarT[n=256][i=128], MbarT[o=128][k=256] (bf16) ----
// AbarT[(h*64+j)][i] = 0.125 * sum_c Wq[i][h*64+c] * Wk[j][h*64+c]
// MbarT[o][(h*64+j)] =         sum_c Wv[j][h*64+c] * Wo[h*64+c][o]
__global__ void prep_kernel(const float* __restrict__ Wq, const float* __restrict__ Wk,
                            const float* __restrict__ Wv, const float* __restrict__ Wo,
                            unsigned short* __restrict__ AbarT,
                            unsigned short* __restrict__ MbarT) {
  int tid = blockIdx.x * blockDim.x + threadIdx.x;   // 65536 threads
  if (tid < 256 * 128) {
    int n = tid >> 7, i = tid & 127;
    int h = n >> 6, j = n & 63;
    const float* wq = Wq + i * 256 + h * 64;
    const float* wk = Wk + j * 256 + h * 64;
    float acc = 0.f;
#pragma unroll 8
    for (int c = 0; c < 64; ++c) acc += wq[c] * wk[c];
    AbarT[n * 128 + i] = f2bf(acc * 0.125f);         // 1/sqrt(64) folded in
  } else {
    int t2 = tid - 256 * 128;
    int o = t2 >> 8, k = t2 & 255;
    int h = k >> 6, j = k & 63;
    const float* wv = Wv + j * 256 + h * 64;
    const float* wo = Wo + (h * 64) * 128 + o;
    float acc = 0.f;
#pragma unroll 8
    for (int c = 0; c < 64; ++c) acc += wv[c] * wo[c * 128];
    MbarT[o * 256 + k] = f2bf(acc);
  }
}

// ---- main fused kernel: 32 pairs / block, 256 threads (4 waves) ----
__global__ __launch_bounds__(256, 4) void attn_kernel(
    const float* __restrict__ z2d, const float* __restrict__ t2d,
    const unsigned short* __restrict__ AbarT, const unsigned short* __restrict__ MbarT,
    const float* __restrict__ bo, float* __restrict__ out) {
  __shared__ __align__(16) unsigned short sT[PB * 256];  // tkv tile, bf16 swizzled (16 KB)
  __shared__ __align__(16) unsigned short sG[PB * 256];  // G then S, bf16 swizzled (16 KB)

  const int tid = threadIdx.x;
  const int P0  = blockIdx.x * PB;

  // ---- stage tkv (t2d[t][P0+p][j]) -> sT, fp32->bf16, swizzled ----
#pragma unroll
  for (int it = 0; it < 8; ++it) {
    int f  = it * 256 + tid;        // 2048 float4 total
    int t  = f >> 9;                // 512 float4 per template
    int rr = f & 511;
    int p  = rr >> 4;
    int j4 = (rr & 15) << 2;
    const float4 v = *(const float4*)(t2d + (size_t)(t * P_ + P0 + p) * 64 + j4);
    ushort4 pk;
    pk.x = f2bf(v.x); pk.y = f2bf(v.y); pk.z = f2bf(v.z); pk.w = f2bf(v.w);
    *(ushort4*)(sT + swz(p, t * 64 + j4)) = pk;
  }
  // no barrier yet: sT/sG first read only after the post-GEMM1 barrier below

  const int wv_  = tid >> 6;   // wave id
  const int lane = tid & 63;
  const int l = lane & 15;     // MFMA: A row / B col / D col
  const int q = lane >> 4;     // MFMA quad: k-group / D row-group
  const int mt = wv_ & 1;      // m-tile (16 rows)
  const int nh = wv_ >> 1;     // n-half

  // ---- GEMM1: G(32x256) = Z(32x128) @ Abar(128x256), bf16 MFMA ----
  // wave covers rows [mt*16, mt*16+16), cols [nh*128, nh*128+128)
  f32x4 acc[8];
#pragma unroll
  for (int i = 0; i < 8; ++i) acc[i] = f32x4{0.f, 0.f, 0.f, 0.f};
  const float* zrow = z2d + (size_t)(P0 + mt * 16 + l) * 128;
#pragma unroll
  for (int kk = 0; kk < 4; ++kk) {
    float4 za = *(const float4*)(zrow + kk * 32 + q * 8);
    float4 zb = *(const float4*)(zrow + kk * 32 + q * 8 + 4);
    short8 af;
    af[0] = (short)f2bf(za.x); af[1] = (short)f2bf(za.y);
    af[2] = (short)f2bf(za.z); af[3] = (short)f2bf(za.w);
    af[4] = (short)f2bf(zb.x); af[5] = (short)f2bf(zb.y);
    af[6] = (short)f2bf(zb.z); af[7] = (short)f2bf(zb.w);
    const unsigned short* bbase = AbarT + (nh * 8) * 2048 + l * 128 + kk * 32 + q * 8;
#pragma unroll
    for (int i = 0; i < 8; ++i) {
      short8 bf = *(const short8*)(bbase + i * 2048);   // n = (nh*8+i)*16 + l
      acc[i] = __builtin_amdgcn_mfma_f32_16x16x32_bf16(af, bf, acc[i], 0, 0, 0);
    }
  }
  // D[m=q*4+r][n=l] -> G[p = mt*16+q*4+r][(nh*8+i)*16+l]  (m89-verified C/D layout)
#pragma unroll
  for (int i = 0; i < 8; ++i) {
    int c = (nh * 8 + i) * 16 + l;
#pragma unroll
    for (int r = 0; r < 4; ++r) {
      int p = mt * 16 + q * 4 + r;
      sG[swz(p, c)] = f2bf(acc[i][r]);
    }
  }
  __syncthreads();

  // ---- attention: 2 lanes per (pair p, head h), 32 channels each ----
  // lane = p*2 + half within the wave; head = wave id. Partial logits over
  // this lane's 32 channels, combined with shfl_xor(1); each lane then writes
  // S for its own 32 channels (slice-private in sG -> no extra barrier).
  {
    const int p    = lane >> 1;
    const int half = lane & 1;
    const int h    = wv_;
    const int c0   = half * 32;
    float lg0 = 0.f, lg1 = 0.f, lg2 = 0.f, lg3 = 0.f;
#pragma unroll
    for (int jj = 0; jj < 4; ++jj) {
      const int cc = c0 + jj * 8;
      short8 g8 = *(const short8*)(sG + swz(p, h * 64 + cc));
      short8 k0 = *(const short8*)(sT + swz(p, cc));
      short8 k1 = *(const short8*)(sT + swz(p, 64 + cc));
      short8 k2 = *(const short8*)(sT + swz(p, 128 + cc));
      short8 k3 = *(const short8*)(sT + swz(p, 192 + cc));
#pragma unroll
      for (int e = 0; e < 8; ++e) {
        float g = bf2f((unsigned short)g8[e]);
        lg0 += g * bf2f((unsigned short)k0[e]);
        lg1 += g * bf2f((unsigned short)k1[e]);
        lg2 += g * bf2f((unsigned short)k2[e]);
        lg3 += g * bf2f((unsigned short)k3[e]);
      }
    }
    lg0 += __shfl_xor(lg0, 1);
    lg1 += __shfl_xor(lg1, 1);
    lg2 += __shfl_xor(lg2, 1);
    lg3 += __shfl_xor(lg3, 1);
    float mx = fmaxf(fmaxf(lg0, lg1), fmaxf(lg2, lg3));
    float e0 = __expf(lg0 - mx), e1 = __expf(lg1 - mx);
    float e2 = __expf(lg2 - mx), e3 = __expf(lg3 - mx);
    float inv = 1.f / (e0 + e1 + e2 + e3);
    e0 *= inv; e1 *= inv; e2 *= inv; e3 *= inv;
    // S[p][h*64+j] = sum_t w_t * tkv[p][t][j], in-place over this lane's own
    // (already consumed) G slice
#pragma unroll
    for (int jj = 0; jj < 4; ++jj) {
      const int cc = c0 + jj * 8;
      short8 k0 = *(const short8*)(sT + swz(p, cc));
      short8 k1 = *(const short8*)(sT + swz(p, 64 + cc));
      short8 k2 = *(const short8*)(sT + swz(p, 128 + cc));
      short8 k3 = *(const short8*)(sT + swz(p, 192 + cc));
      short8 sv;
#pragma unroll
      for (int e = 0; e < 8; ++e) {
        float s = e0 * bf2f((unsigned short)k0[e]) + e1 * bf2f((unsigned short)k1[e])
                + e2 * bf2f((unsigned short)k2[e]) + e3 * bf2f((unsigned short)k3[e]);
        sv[e] = (short)f2bf(s);
      }
      *(short8*)(sG + swz(p, h * 64 + cc)) = sv;
    }
  }
  __syncthreads();

  // ---- GEMM2: OUT(32x128) = S(32x256) @ Mbar(256x128) + bo ----
  // wave covers rows [mt*16, mt*16+16), cols [nh*64, nh*64+64)
  f32x4 acc2[4];
#pragma unroll
  for (int i = 0; i < 4; ++i) acc2[i] = f32x4{0.f, 0.f, 0.f, 0.f};
#pragma unroll
  for (int kk = 0; kk < 8; ++kk) {
    const int p  = mt * 16 + l;
    const int cb = kk * 32 + q * 8;          // cb % 8 == 0 -> one 16B block
    short8 af2 = *(const short8*)(sG + p * 256 + (((cb >> 3) ^ (p & 31)) << 3));
    const unsigned short* mb = MbarT + (size_t)(nh * 64 + l) * 256 + kk * 32 + q * 8;
#pragma unroll
    for (int i = 0; i < 4; ++i) {
      short8 bf = *(const short8*)(mb + i * 16 * 256);   // o = nh*64 + i*16 + l
      acc2[i] = __builtin_amdgcn_mfma_f32_16x16x32_bf16(af2, bf, acc2[i], 0, 0, 0);
    }
  }
#pragma unroll
  for (int i = 0; i < 4; ++i) {
    const int o   = nh * 64 + i * 16 + l;
    const float b = bo[o];
#pragma unroll
    for (int r = 0; r < 4; ++r) {
      size_t row = (size_t)(P0 + mt * 16 + q * 4 + r);
      out[row * 128 + o] = acc2[i][r] + b;
    }
  }
}

extern "C" void kernel_launch(void* const* d_in, const int* in_sizes, int n_in,
                              void* d_out, int out_size, void* d_ws, size_t ws_size,
                              hipStream_t stream) {
  const float* z2d = (const float*)d_in[0];
  const float* t2d = (const float*)d_in[1];
  const float* Wq  = (const float*)d_in[2];
  const float* Wk  = (const float*)d_in[3];
  const float* Wv  = (const float*)d_in[4];
  const float* Wo  = (const float*)d_in[5];
  const float* bo  = (const float*)d_in[6];

  unsigned short* AbarT = (unsigned short*)d_ws;           // 256*128 bf16 = 64 KB
  unsigned short* MbarT = AbarT + 256 * 128;               // 128*256 bf16 = 64 KB
  float* out = (float*)d_out;

  hipLaunchKernelGGL(prep_kernel, dim3(256), dim3(256), 0, stream,
                     Wq, Wk, Wv, Wo, AbarT, MbarT);
  hipLaunchKernelGGL(attn_kernel, dim3(NBLK), dim3(256), 0, stream,
                     z2d, t2d, AbarT, MbarT, bo, out);
}

// Round 2
// 372.061 us; speedup vs baseline: 1.0601x; 1.0601x over previous
//
#include <hip/hip_runtime.h>

// TemplatePointwiseAttention, MI355X/gfx950.
// Folded-weight formulation: G = Z @ Abar (MFMA), 4-way softmax, OUT = S @ Mbar.
// This revision: PERSISTENT blocks. 512 blocks (1/CU, forced by 128 KB LDS),
// 512 threads (8 waves), each block loops over 9 tiles of 32 pairs.
//  - Abar (64 KB) staged once into LDS (XOR-swizzled) -> GEMM1 B from ds_read_b128
//  - Mbar held in VGPRs (64/lane, wave-sliced)        -> GEMM2 B loads: zero/tile
//  - sT, sG double-buffered (2x16KB each) -> 2-phase/2-barrier pipeline per tile:
//      X: [GEMM2(i-1)+store || GEMM1(i) || issue stage loads for i+1 (T14 split)]
//      Y: [attention(i)]
// Rationale: R1 showed latency-bound (VALUBusy 17%, MfmaUtil 3.7%, dur 207us =
// 497k cy/CU vs ~90k of issue demand) with per-block weight reloads + 3 barrier
// drains per tile as the serial chain. This removes the reloads and hides
// staging latency under compute.

#define R_    384
#define P_    (R_ * R_)      // 147456 residue pairs
#define PB    32             // pairs per tile
#define NPB   512            // persistent blocks
#define NT_   ((P_ / PB) / NPB)   // 9 tiles per block

typedef __attribute__((ext_vector_type(8))) short  short8;   // 8 x bf16 MFMA frag
typedef __attribute__((ext_vector_type(4))) float  f32x4;    // MFMA accumulator

__device__ __forceinline__ unsigned short f2bf(float f) {
  unsigned u = __float_as_uint(f);
  unsigned r = ((u >> 16) & 1u) + 0x7FFFu;   // RNE
  return (unsigned short)((u + r) >> 16);
}
__device__ __forceinline__ float bf2f(unsigned short s) {
  return __uint_as_float(((unsigned)s) << 16);
}
// LDS layout for [p][c] tiles (p<32, c<256), bf16, pitch 256, XOR-swizzled in
// 16B blocks (c>>3 ^ p&31).
__device__ __forceinline__ int swz(int p, int c) {
  return p * 256 + ((((c >> 3) ^ (p & 31)) << 3) | (c & 7));
}

// ---- K0: fold weights into AbarT[n=256][i=128], MbarT[o=128][k=256] (bf16) ----
__global__ void prep_kernel(const float* __restrict__ Wq, const float* __restrict__ Wk,
                            const float* __restrict__ Wv, const float* __restrict__ Wo,
                            unsigned short* __restrict__ AbarT,
                            unsigned short* __restrict__ MbarT) {
  int tid = blockIdx.x * blockDim.x + threadIdx.x;   // 65536 threads
  if (tid < 256 * 128) {
    int n = tid >> 7, i = tid & 127;
    int h = n >> 6, j = n & 63;
    const float* wq = Wq + i * 256 + h * 64;
    const float* wk = Wk + j * 256 + h * 64;
    float acc = 0.f;
#pragma unroll 8
    for (int c = 0; c < 64; ++c) acc += wq[c] * wk[c];
    AbarT[n * 128 + i] = f2bf(acc * 0.125f);         // 1/sqrt(64) folded in
  } else {
    int t2 = tid - 256 * 128;
    int o = t2 >> 8, k = t2 & 255;
    int h = k >> 6, j = k & 63;
    const float* wv = Wv + j * 256 + h * 64;
    const float* wo = Wo + (h * 64) * 128 + o;
    float acc = 0.f;
#pragma unroll 8
    for (int c = 0; c < 64; ++c) acc += wv[c] * wo[c * 128];
    MbarT[o * 256 + k] = f2bf(acc);
  }
}

// ---- persistent fused kernel ----
__global__ __launch_bounds__(512, 2) void attn_kernel(
    const float* __restrict__ z2d, const float* __restrict__ t2d,
    const unsigned short* __restrict__ AbarT, const unsigned short* __restrict__ MbarT,
    const float* __restrict__ bo, float* __restrict__ out) {
  extern __shared__ unsigned short smem[];
  unsigned short* sAbar = smem;            // [256][128] swizzled, 64 KB
  unsigned short* sT    = smem + 32768;    // 2 x [32][256] swizzled, 2x16 KB
  unsigned short* sG    = smem + 49152;    // 2 x [32][256] swizzled, 2x16 KB

  const int tid  = threadIdx.x;
  const int wv_  = tid >> 6;
  const int lane = tid & 63;
  const int l = lane & 15;     // MFMA: A row / B col / D col
  const int q = lane >> 4;     // MFMA quad
  const int mt = wv_ & 1;      // m-tile (16 rows of the 32-pair tile)
  const int ng = wv_ >> 1;     // GEMM1 n-group: 4 n-tiles of 16
  const int nd = wv_ >> 1;     // GEMM2 n-group: 2 o-tiles of 16

  // ---- prologue: Abar -> LDS (swizzled) ----
#pragma unroll
  for (int k2 = 0; k2 < 8; ++k2) {
    int id = k2 * 512 + tid;               // 4096 chunks of 8 el
    int n = id >> 4, blk = id & 15;
    short8 v = *(const short8*)(AbarT + n * 128 + blk * 8);
    *(short8*)(sAbar + n * 128 + ((blk ^ (n & 15)) << 3)) = v;
  }
  // ---- Mbar -> regs (wave-sliced: 2 o-tiles x 8 kk = 64 VGPRs/lane) ----
  short8 mb[2][8];
#pragma unroll
  for (int j = 0; j < 2; ++j)
#pragma unroll
    for (int kk = 0; kk < 8; ++kk)
      mb[j][kk] = *(const short8*)(MbarT + (size_t)((nd * 2 + j) * 16 + l) * 256 + kk * 32 + q * 8);
  const float bo0 = bo[(nd * 2) * 16 + l];
  const float bo1 = bo[(nd * 2 + 1) * 16 + l];

  float4 zp[8];   // z prefetch for next tile (raw fp32)
  float4 st[4];   // t2d staging regs (T14 issue-early/write-late)

  // ---- stage tile 0 (sT[0]) + z prefetch tile 0 ----
  {
    const size_t P00 = (size_t)blockIdx.x * PB;
#pragma unroll
    for (int k2 = 0; k2 < 4; ++k2) {
      int f = k2 * 512 + tid;              // 2048 float4
      int t = f >> 9, rr = f & 511;
      int p2 = rr >> 4, j4 = (rr & 15) << 2;
      float4 v = *(const float4*)(t2d + ((size_t)t * P_ + P00 + p2) * 64 + j4);
      ushort4 pk;
      pk.x = f2bf(v.x); pk.y = f2bf(v.y); pk.z = f2bf(v.z); pk.w = f2bf(v.w);
      *(ushort4*)(sT + swz(p2, t * 64 + j4)) = pk;
    }
    const float* zr = z2d + (P00 + mt * 16 + l) * 128;
#pragma unroll
    for (int kk = 0; kk < 4; ++kk) {
      zp[2 * kk]     = *(const float4*)(zr + kk * 32 + q * 8);
      zp[2 * kk + 1] = *(const float4*)(zr + kk * 32 + q * 8 + 4);
    }
  }
  __syncthreads();

#pragma unroll 1
  for (int it = 0; it < NT_; ++it) {
    const int curT = it & 1, nxtT = curT ^ 1;
    const size_t P0  = (size_t)(blockIdx.x + it * NPB) * PB;
    const size_t P0n = (size_t)(blockIdx.x + (it + 1) * NPB) * PB;
    const bool more = (it + 1 < NT_);

    // ======== phase X ========
    // (1) issue t2d staging loads for tile i+1 (write deferred to (6))
    if (more) {
#pragma unroll
      for (int k2 = 0; k2 < 4; ++k2) {
        int f = k2 * 512 + tid;
        int t = f >> 9, rr = f & 511;
        int p2 = rr >> 4, j4 = (rr & 15) << 2;
        st[k2] = *(const float4*)(t2d + ((size_t)t * P_ + P0n + p2) * 64 + j4);
      }
    }
    // (2) convert this tile's z prefetch -> A fragments
    short8 af[4];
#pragma unroll
    for (int kk = 0; kk < 4; ++kk) {
      af[kk][0] = (short)f2bf(zp[2 * kk].x);     af[kk][1] = (short)f2bf(zp[2 * kk].y);
      af[kk][2] = (short)f2bf(zp[2 * kk].z);     af[kk][3] = (short)f2bf(zp[2 * kk].w);
      af[kk][4] = (short)f2bf(zp[2 * kk + 1].x); af[kk][5] = (short)f2bf(zp[2 * kk + 1].y);
      af[kk][6] = (short)f2bf(zp[2 * kk + 1].z); af[kk][7] = (short)f2bf(zp[2 * kk + 1].w);
    }
    // (3) issue z loads for tile i+1
    if (more) {
      const float* zr = z2d + (P0n + mt * 16 + l) * 128;
#pragma unroll
      for (int kk = 0; kk < 4; ++kk) {
        zp[2 * kk]     = *(const float4*)(zr + kk * 32 + q * 8);
        zp[2 * kk + 1] = *(const float4*)(zr + kk * 32 + q * 8 + 4);
      }
    }
    // (4) GEMM2 for tile i-1: S(sG[prv]) @ Mbar(regs) -> out
    if (it > 0) {
      const unsigned short* sGp = sG + nxtT * 8192;   // (it-1)&1 == nxtT
      f32x4 acc2[2];
      acc2[0] = f32x4{0.f, 0.f, 0.f, 0.f};
      acc2[1] = f32x4{0.f, 0.f, 0.f, 0.f};
      const int p2 = mt * 16 + l;
#pragma unroll
      for (int kk = 0; kk < 8; ++kk) {
        short8 af2 = *(const short8*)(sGp + p2 * 256 + (((kk * 4 + q) ^ (p2 & 31)) << 3));
        acc2[0] = __builtin_amdgcn_mfma_f32_16x16x32_bf16(af2, mb[0][kk], acc2[0], 0, 0, 0);
        acc2[1] = __builtin_amdgcn_mfma_f32_16x16x32_bf16(af2, mb[1][kk], acc2[1], 0, 0, 0);
      }
      const size_t P0p = P0 - (size_t)NPB * PB;
#pragma unroll
      for (int j = 0; j < 2; ++j) {
        const int o = (nd * 2 + j) * 16 + l;
        const float bj = j ? bo1 : bo0;
#pragma unroll
        for (int r = 0; r < 4; ++r) {
          out[(P0p + mt * 16 + q * 4 + r) * 128 + o] = acc2[j][r] + bj;
        }
      }
    }
    // (5) GEMM1 tile i: Z(af regs) @ Abar(LDS) -> G -> sG[curT]
    {
      f32x4 acc1[4];
#pragma unroll
      for (int i = 0; i < 4; ++i) acc1[i] = f32x4{0.f, 0.f, 0.f, 0.f};
#pragma unroll
      for (int kk = 0; kk < 4; ++kk) {
#pragma unroll
        for (int i = 0; i < 4; ++i) {
          const int n = (ng * 4 + i) * 16 + l;
          short8 bf = *(const short8*)(sAbar + n * 128 + (((kk * 4 + q) ^ l) << 3));
          acc1[i] = __builtin_amdgcn_mfma_f32_16x16x32_bf16(af[kk], bf, acc1[i], 0, 0, 0);
        }
      }
      unsigned short* sGc = sG + curT * 8192;
#pragma unroll
      for (int i = 0; i < 4; ++i) {
        const int c = (ng * 4 + i) * 16 + l;
#pragma unroll
        for (int r = 0; r < 4; ++r) {
          const int p2 = mt * 16 + q * 4 + r;
          sGc[swz(p2, c)] = f2bf(acc1[i][r]);    // D[m=q*4+r][n=l], m89-verified
        }
      }
    }
    // (6) write staged t2d regs -> sT[nxt] (loads have had G2+G1 time to land)
    if (more) {
      unsigned short* sTn = sT + nxtT * 8192;
#pragma unroll
      for (int k2 = 0; k2 < 4; ++k2) {
        int f = k2 * 512 + tid;
        int t = f >> 9, rr = f & 511;
        int p2 = rr >> 4, j4 = (rr & 15) << 2;
        ushort4 pk;
        pk.x = f2bf(st[k2].x); pk.y = f2bf(st[k2].y);
        pk.z = f2bf(st[k2].z); pk.w = f2bf(st[k2].w);
        *(ushort4*)(sTn + swz(p2, t * 64 + j4)) = pk;
      }
    }
    __syncthreads();

    // ======== phase Y: attention ========
    // thread = (pair p, head h, quarter u2): 16 channels each; logits combined
    // across the 4 quarter-lanes via shfl_xor(1),(2).
    {
      const int p   = tid >> 4;
      const int sub = tid & 15;
      const int h   = sub >> 2;
      const int u2  = sub & 3;
      const int c0  = h * 64 + u2 * 16;
      unsigned short* sGc = sG + curT * 8192;
      const unsigned short* sTc = sT + curT * 8192;
      short8 g0 = *(const short8*)(sGc + swz(p, c0));
      short8 g1 = *(const short8*)(sGc + swz(p, c0 + 8));
      short8 kc[4][2];
#pragma unroll
      for (int t = 0; t < 4; ++t) {
        kc[t][0] = *(const short8*)(sTc + swz(p, t * 64 + u2 * 16));
        kc[t][1] = *(const short8*)(sTc + swz(p, t * 64 + u2 * 16 + 8));
      }
      float lg0 = 0.f, lg1 = 0.f, lg2 = 0.f, lg3 = 0.f;
#pragma unroll
      for (int e = 0; e < 8; ++e) {
        const float ga = bf2f((unsigned short)g0[e]);
        const float gb = bf2f((unsigned short)g1[e]);
        lg0 += ga * bf2f((unsigned short)kc[0][0][e]) + gb * bf2f((unsigned short)kc[0][1][e]);
        lg1 += ga * bf2f((unsigned short)kc[1][0][e]) + gb * bf2f((unsigned short)kc[1][1][e]);
        lg2 += ga * bf2f((unsigned short)kc[2][0][e]) + gb * bf2f((unsigned short)kc[2][1][e]);
        lg3 += ga * bf2f((unsigned short)kc[3][0][e]) + gb * bf2f((unsigned short)kc[3][1][e]);
      }
      lg0 += __shfl_xor(lg0, 1); lg0 += __shfl_xor(lg0, 2);
      lg1 += __shfl_xor(lg1, 1); lg1 += __shfl_xor(lg1, 2);
      lg2 += __shfl_xor(lg2, 1); lg2 += __shfl_xor(lg2, 2);
      lg3 += __shfl_xor(lg3, 1); lg3 += __shfl_xor(lg3, 2);
      float mx = fmaxf(fmaxf(lg0, lg1), fmaxf(lg2, lg3));
      float e0 = __expf(lg0 - mx), e1 = __expf(lg1 - mx);
      float e2 = __expf(lg2 - mx), e3 = __expf(lg3 - mx);
      float inv = 1.f / (e0 + e1 + e2 + e3);
      e0 *= inv; e1 *= inv; e2 *= inv; e3 *= inv;
#pragma unroll
      for (int u = 0; u < 2; ++u) {
        short8 sv;
#pragma unroll
        for (int e = 0; e < 8; ++e) {
          float s = e0 * bf2f((unsigned short)kc[0][u][e]) + e1 * bf2f((unsigned short)kc[1][u][e])
                  + e2 * bf2f((unsigned short)kc[2][u][e]) + e3 * bf2f((unsigned short)kc[3][u][e]);
          sv[e] = (short)f2bf(s);
        }
        *(short8*)(sGc + swz(p, c0 + u * 8)) = sv;
      }
    }
    __syncthreads();
  }

  // ---- tail: GEMM2 for the last tile ----
  {
    const int prv = (NT_ - 1) & 1;
    const unsigned short* sGp = sG + prv * 8192;
    f32x4 acc2[2];
    acc2[0] = f32x4{0.f, 0.f, 0.f, 0.f};
    acc2[1] = f32x4{0.f, 0.f, 0.f, 0.f};
    const int p2 = mt * 16 + l;
#pragma unroll
    for (int kk = 0; kk < 8; ++kk) {
      short8 af2 = *(const short8*)(sGp + p2 * 256 + (((kk * 4 + q) ^ (p2 & 31)) << 3));
      acc2[0] = __builtin_amdgcn_mfma_f32_16x16x32_bf16(af2, mb[0][kk], acc2[0], 0, 0, 0);
      acc2[1] = __builtin_amdgcn_mfma_f32_16x16x32_bf16(af2, mb[1][kk], acc2[1], 0, 0, 0);
    }
    const size_t P0p = (size_t)(blockIdx.x + (NT_ - 1) * NPB) * PB;
#pragma unroll
    for (int j = 0; j < 2; ++j) {
      const int o = (nd * 2 + j) * 16 + l;
      const float bj = j ? bo1 : bo0;
#pragma unroll
      for (int r = 0; r < 4; ++r) {
        out[(P0p + mt * 16 + q * 4 + r) * 128 + o] = acc2[j][r] + bj;
      }
    }
  }
}

extern "C" void kernel_launch(void* const* d_in, const int* in_sizes, int n_in,
                              void* d_out, int out_size, void* d_ws, size_t ws_size,
                              hipStream_t stream) {
  const float* z2d = (const float*)d_in[0];
  const float* t2d = (const float*)d_in[1];
  const float* Wq  = (const float*)d_in[2];
  const float* Wk  = (const float*)d_in[3];
  const float* Wv  = (const float*)d_in[4];
  const float* Wo  = (const float*)d_in[5];
  const float* bo  = (const float*)d_in[6];

  unsigned short* AbarT = (unsigned short*)d_ws;           // 256*128 bf16 = 64 KB
  unsigned short* MbarT = AbarT + 256 * 128;               // 128*256 bf16 = 64 KB
  float* out = (float*)d_out;

  static bool attr_set = false;
  if (!attr_set) {
    (void)hipFuncSetAttribute((const void*)attn_kernel,
                              hipFuncAttributeMaxDynamicSharedMemorySize, 131072);
    attr_set = true;
  }

  hipLaunchKernelGGL(prep_kernel, dim3(256), dim3(256), 0, stream,
                     Wq, Wk, Wv, Wo, AbarT, MbarT);
  hipLaunchKernelGGL(attn_kernel, dim3(NPB), dim3(512), 131072, stream,
                     z2d, t2d, AbarT, MbarT, bo, out);
}